// Round 3
// baseline (505.089 us; speedup 1.0000x reference)
//
#include <hip/hip_runtime.h>
#include <cstdint>
#include <cstddef>

// ---------------- problem constants ----------------
#define T_REAL 14884        // 4*61*61 real pixels
#define TPAD   15360        // padded to 30*512
#define CDIM   256
#define HW     3721         // 61*61
#define NRB    30           // row blocks of 512
#define NSL    16           // column slices (grid.y)
#define TPS    15           // tiles per slice (240/16)
#define NPADJ  476.0f       // TPAD - T_REAL

// feats are stored pre-scaled by sqrt(log2(e)/0.07) so the MFMA output IS
// sim*log2(e)/temperature, ready for exp2 with no per-element multiply.
static constexpr float SQRT_SCALE = 4.53981598f;   // sqrt(20.6099291555566)

typedef _Float16 f16x8  __attribute__((ext_vector_type(8)));
typedef float    f32x16 __attribute__((ext_vector_type(16)));

__device__ __forceinline__ float exp2_fast(float x) {
#if __has_builtin(__builtin_amdgcn_exp2f)
    return __builtin_amdgcn_exp2f(x);
#else
    return exp2f(x);
#endif
}

// ---------------- workspace layout (bytes) ----------------
#define OFF_FEATS 0u
#define SZ_FEATS  ((unsigned)TPAD * CDIM * 2u)            // 7,864,320
#define OFF_LAB   (OFF_FEATS + SZ_FEATS)                  // TPAD ints
#define OFF_PART  (OFF_LAB + (unsigned)TPAD * 4u)         // NRB*NSL*512 float2
#define SZ_PART   ((unsigned)NRB * NSL * 512u * 8u)
#define OFF_ACC   (OFF_PART + SZ_PART)                    // 2 floats

// ---------------- k_prep: fused init+norm+transpose+scale+cast ----------------
// grid (60, 4) x 256. Blocks bx<59: 64 pixels each. Block bx==59 (per n):
// zeroes 119 pad rows, writes pad labels, zeroes accum.
__global__ void k_prep(const float* __restrict__ emb, const int* __restrict__ targets,
                       _Float16* __restrict__ feats, int* __restrict__ labels,
                       float* __restrict__ accum) {
    const int tid = threadIdx.x;
    const int bx = blockIdx.x, n = blockIdx.y;

    if (bx == 59) {            // init-tail block (uniform branch, no barrier after)
        const int r0 = T_REAL + n * 119;
        f16x8 z = {0, 0, 0, 0, 0, 0, 0, 0};
        for (int c = tid; c < 119 * 32; c += 256) {
            int rr = r0 + (c >> 5), cc = c & 31;
            *reinterpret_cast<f16x8*>(feats + (size_t)rr * CDIM + cc * 8) = z;
        }
        for (int t = tid; t < 119; t += 256) labels[r0 + t] = -1;
        if (n == 0 && tid == 0) { accum[0] = 0.f; accum[1] = 0.f; }
        return;
    }

    __shared__ float tile[64][257];
    __shared__ float sspart[4][64];
    const int lane = tid & 63, w = tid >> 6;
    const int px0 = bx * 64;
    const int hw = px0 + lane;

    if (tid < 64) {
        const int hwl = px0 + tid;
        if (hwl < HW) labels[n * HW + hwl] = targets[n * HW + hwl];
    }

    float ssq = 0.f;
    for (int ci = w; ci < CDIM; ci += 4) {
        float v = (hw < HW) ? emb[((size_t)(n * CDIM + ci)) * HW + hw] : 0.f;
        tile[lane][ci] = v;
        ssq += v * v;
    }
    sspart[w][lane] = ssq;
    __syncthreads();

    const int pp = tid >> 2, q = tid & 3;     // pixel-in-tile, channel quarter
    float s2 = sspart[q][pp];
    s2 += __shfl_xor(s2, 1);
    s2 += __shfl_xor(s2, 2);
    const float inv = SQRT_SCALE / fmaxf(sqrtf(s2), 1e-12f);

    const int hwp = px0 + pp;
    if (hwp < HW) {
        _Float16* dst = feats + ((size_t)(n * HW + hwp)) * CDIM + q * 64;
#pragma unroll
        for (int g = 0; g < 8; ++g) {
            const int gg = g ^ q;             // spread LDS banks across q
            f16x8 o;
#pragma unroll
            for (int e = 0; e < 8; ++e) o[e] = (_Float16)(tile[pp][q * 64 + gg * 8 + e] * inv);
            *reinterpret_cast<f16x8*>(dst + gg * 8) = o;
        }
    }
}

// ---------------- k_main staging ----------------
// LDS tile: 64 j-rows x 256 halves (32 chunks of 16B per row). Slot chunk c of
// row j holds global chunk c ^ swz(j), swz(j) = (j&7) ^ (((j>>3)&3)<<1).
// Linear LDS dest + pre-swizzled global source (rule #21). 4 loads/thread.
__device__ __forceinline__ void stage_tile(const _Float16* __restrict__ feats, int jbase,
                                           _Float16* bufp, int tid) {
#pragma unroll
    for (int sweep = 0; sweep < 4; ++sweep) {
        int ch = sweep * 512 + tid;          // 0..2047 = 64 rows * 32 chunks
        int j  = ch >> 5;
        int c  = ch & 31;
        int swz = (j & 7) ^ (((j >> 3) & 3) << 1);
        int csrc = c ^ swz;
        const _Float16* src = feats + ((size_t)(jbase + j)) * CDIM + csrc * 8;
        __builtin_amdgcn_global_load_lds(
            (const __attribute__((address_space(1))) void*)src,
            (__attribute__((address_space(3))) void*)(bufp + (size_t)ch * 8),
            16, 0, 0);
    }
}

// ---------------- k_main: fused sim/exp/masked-rowsum ----------------
// 8 waves x 64 i-rows = 512 rows/block. Per wave: B = 2 i-groups of 32 in
// registers (64 VGPR), A = 64-j tile from LDS. Accumulators (32 regs) are
// REUSED between the two j-groups to keep total regs <= 128 -> 2 blocks/CU.
__global__ __launch_bounds__(512, 4) void k_main(const _Float16* __restrict__ feats,
                                                 const int* __restrict__ labels,
                                                 float2* __restrict__ partials) {
    __shared__ __align__(16) _Float16 buf[2][64 * 256];   // 2 x 32KB
    const int tid  = threadIdx.x;
    const int w    = tid >> 6, lane = tid & 63;
    const int lo   = lane & 31, hi = lane >> 5;
    const int rb = blockIdx.x, slice = blockIdx.y;
    const int ibase = rb * 512 + w * 64;

    const int labi0 = labels[ibase + lo];
    const int labi1 = labels[ibase + 32 + lo];

    // B fragments (i-side), resident all kernel.
    // 32x32x16 B layout: lane holds col = lane&31, k = (lane>>5)*8 + e.
    f16x8 b0[16], b1[16];
    {
        const f16x8* r0 = (const f16x8*)(feats + (size_t)(ibase + lo) * CDIM + hi * 8);
        const f16x8* r1 = (const f16x8*)(feats + (size_t)(ibase + 32 + lo) * CDIM + hi * 8);
#pragma unroll
        for (int k = 0; k < 16; ++k) { b0[k] = r0[k * 2]; b1[k] = r1[k * 2]; }
    }

    // zero-VALU swizzled read addressing: slot(k,hi) = (2k+hi) ^ swz(lo)
    // halves offset = lo*256 + 8*(hi^s0) + 16*((k&3)^sp) + 16*(k&12) [+8192 jg1]
    const int s  = (lo & 7) ^ (((lo >> 3) & 3) << 1);
    const int s0 = s & 1, sp = (s >> 1) & 3;
    int hidx[4];
#pragma unroll
    for (int m = 0; m < 4; ++m)
        hidx[m] = lo * 256 + ((hi ^ s0) << 3) + ((m ^ sp) << 4);

    float accA0 = 0.f, accP0 = 0.f, accA1 = 0.f, accP1 = 0.f;
    _Float16* ldsbase = &buf[0][0];

    stage_tile(feats, slice * 64, ldsbase, tid);

#pragma unroll 1
    for (int ti = 0; ti < TPS; ++ti) {
        const int jt = slice + ti * NSL;

        __builtin_amdgcn_s_barrier();              // prev compute done everywhere
        __builtin_amdgcn_sched_barrier(0);
        if (ti + 1 < TPS) {
            stage_tile(feats, (jt + NSL) * 64, &buf[(ti + 1) & 1][0], tid);
            asm volatile("s_waitcnt vmcnt(4)" ::: "memory");  // tile ti done; ti+1 in flight
        } else {
            asm volatile("s_waitcnt vmcnt(0)" ::: "memory");
        }
        __builtin_amdgcn_s_barrier();              // tile ti visible to all waves
        __builtin_amdgcn_sched_barrier(0);

        const _Float16* bc = &buf[ti & 1][0];

#pragma unroll
        for (int jg = 0; jg < 2; ++jg) {
            const int jgo = jg * 8192;             // +32 rows in halves
            f32x16 cA = {0,0,0,0,0,0,0,0,0,0,0,0,0,0,0,0};
            f32x16 cB = cA;
#pragma unroll
            for (int k = 0; k < 16; ++k) {
                const f16x8 a = *reinterpret_cast<const f16x8*>(
                    bc + jgo + hidx[k & 3] + ((k & 12) << 4));
                cA = __builtin_amdgcn_mfma_f32_32x32x16_f16(a, b0[k], cA, 0, 0, 0);
                cB = __builtin_amdgcn_mfma_f32_32x32x16_f16(a, b1[k], cB, 0, 0, 0);
            }
            // epilogue: C/D layout col(i)=lane&31, row(j)=(reg&3)+8*(reg>>2)+4*hi
            const int jb2 = jt * 64 + jg * 32;
#pragma unroll
            for (int q = 0; q < 4; ++q) {
                const int4 lj = *reinterpret_cast<const int4*>(labels + jb2 + q * 8 + hi * 4);
#pragma unroll
                for (int r = 0; r < 4; ++r) {
                    const int ljr = (r == 0) ? lj.x : (r == 1) ? lj.y : (r == 2) ? lj.z : lj.w;
                    float e0 = exp2_fast(cA[q * 4 + r]);
                    accA0 += e0;
                    accP0 += (ljr == labi0) ? e0 : 0.f;
                    float e1 = exp2_fast(cB[q * 4 + r]);
                    accA1 += e1;
                    accP1 += (ljr == labi1) ? e1 : 0.f;
                }
            }
        }
    }

    // diagonal term: ||b_i||^2 (feats pre-scaled, so this IS sim_ii*SCALE)
    float n0 = 0.f, n1 = 0.f;
#pragma unroll
    for (int k = 0; k < 16; ++k)
#pragma unroll
        for (int e = 0; e < 8; ++e) {
            float v0 = (float)b0[k][e]; n0 += v0 * v0;
            float v1 = (float)b1[k][e]; n1 += v1 * v1;
        }
    n0 += __shfl_xor(n0, 32); n1 += __shfl_xor(n1, 32);

    // merge the two k-halves (lanes l and l^32 hold the same i)
    accA0 += __shfl_xor(accA0, 32); accP0 += __shfl_xor(accP0, 32);
    accA1 += __shfl_xor(accA1, 32); accP1 += __shfl_xor(accP1, 32);

    // subtract diagonal exactly once (owner slice of the tile containing j==i)
    if (((rb * 8 + w) & (NSL - 1)) == slice) {
        float e0 = exp2_fast(n0), e1 = exp2_fast(n1);
        accA0 -= e0; accP0 -= e0;
        accA1 -= e1; accP1 -= e1;
    }

    if (hi == 0) {
        size_t base = ((size_t)(rb * NSL + slice)) * 512 + w * 64;
        partials[base + lo]      = make_float2(accA0, accP0);
        partials[base + 32 + lo] = make_float2(accA1, accP1);
    }
}

// ---------------- k_reduce: per-row loss + global accumulate ----------------
__global__ void k_reduce(const float2* __restrict__ partials, float* __restrict__ accum) {
    const int rb = blockIdx.x;          // 30
    const int rl = threadIdx.x;         // 512
    const int t  = rb * 512 + rl;
    float sA = -NPADJ, sP = 0.f;        // pad columns contribute exp2(0)=1 each
#pragma unroll
    for (int s = 0; s < NSL; ++s) {
        float2 v = partials[((size_t)(rb * NSL + s)) * 512 + rl];
        sA += v.x; sP += v.y;
    }
    float per = 0.f, cnt = 0.f;
    if (t < T_REAL && sP > 0.f) {
        per = logf(sA) - logf(sP);      // = -(log(pos) - log(all))
        cnt = 1.f;
    }
#pragma unroll
    for (int off = 32; off >= 1; off >>= 1) {
        per += __shfl_xor(per, off);
        cnt += __shfl_xor(cnt, off);
    }
    if ((threadIdx.x & 63) == 0) { atomicAdd(&accum[0], per); atomicAdd(&accum[1], cnt); }
}

__global__ void k_final(const float* __restrict__ accum, float* __restrict__ out) {
    out[0] = accum[0] / fmaxf(accum[1], 1.0f);
}

// ---------------- launch ----------------
extern "C" void kernel_launch(void* const* d_in, const int* in_sizes, int n_in,
                              void* d_out, int out_size, void* d_ws, size_t ws_size,
                              hipStream_t stream) {
    const float* emb     = (const float*)d_in[0];
    const int*   targets = (const int*)d_in[1];
    float*       out     = (float*)d_out;
    char*        ws      = (char*)d_ws;

    _Float16* feats    = (_Float16*)(ws + OFF_FEATS);
    int*      labels   = (int*)(ws + OFF_LAB);
    float2*   partials = (float2*)(ws + OFF_PART);
    float*    accum    = (float*)(ws + OFF_ACC);

    k_prep  <<<dim3(60, 4),    dim3(256), 0, stream>>>(emb, targets, feats, labels, accum);
    k_main  <<<dim3(NRB, NSL), dim3(512), 0, stream>>>(feats, labels, partials);
    k_reduce<<<dim3(NRB),      dim3(512), 0, stream>>>(partials, accum);
    k_final <<<dim3(1),        dim3(1),   0, stream>>>(accum, out);
}

// Round 6
// 231.103 us; speedup vs baseline: 2.1856x; 2.1856x over previous
//
#include <hip/hip_runtime.h>
#include <cstdint>
#include <cstddef>

// ---------------- problem constants ----------------
#define T_REAL 14884        // 4*61*61 real pixels
#define TPAD   15360        // padded to 60*256
#define CDIM   256
#define HW     3721         // 61*61
#define NRB    60           // row blocks of 256 (4 waves x 64 rows)
#define NSL    16           // column slices (grid.y)
#define TPS    15           // 64-wide j-tiles per slice (240/16)
#define NT     240          // total j-tiles
#define NPADJ  476.0f       // TPAD - T_REAL

// feats are stored pre-scaled by sqrt(log2(e)/0.07) so the MFMA output IS
// sim*log2(e)/temperature, ready for exp2 with no per-element multiply.
static constexpr float SQRT_SCALE = 4.53981598f;   // sqrt(20.6099291555566)

typedef _Float16 f16x8  __attribute__((ext_vector_type(8)));
typedef float    f32x16 __attribute__((ext_vector_type(16)));

__device__ __forceinline__ float exp2_fast(float x) {
#if __has_builtin(__builtin_amdgcn_exp2f)
    return __builtin_amdgcn_exp2f(x);
#else
    return exp2f(x);
#endif
}

// ---------------- workspace layout (bytes) ----------------
#define OFF_FEATS 0u
#define SZ_FEATS  ((unsigned)TPAD * CDIM * 2u)            // 7,864,320
#define OFF_LAB   (OFF_FEATS + SZ_FEATS)                  // TPAD ints
#define OFF_RANK  (OFF_LAB + (unsigned)TPAD * 4u)         // T_REAL ints (rounded)
#define OFF_CTL   (OFF_RANK + 59648u)                     // int[32]: hist/cnt/offs
#define OFF_TCL   (OFF_CTL + 128u)                        // NT ints -> 1024
#define OFF_PART  (OFF_TCL + 1024u)                       // NRB*NSL*256 float2
#define SZ_PART   ((unsigned)NRB * NSL * 256u * 8u)       // 1,966,080
#define OFF_ACC   (OFF_PART + SZ_PART)                    // 2 floats

// ctl layout (ints): [0..4]=hist, [8..12]=cnt (scatter cursors), [16..21]=offs

// ---------------- k_zero ----------------
__global__ void k_zero(int* __restrict__ ctl, float* __restrict__ accum) {
    int t = threadIdx.x;
    if (t < 32) ctl[t] = 0;
    if (t == 32) { accum[0] = 0.f; accum[1] = 0.f; }
}

// ---------------- k_hist: per-class counts ----------------
__global__ void k_hist(const int* __restrict__ targets, int* __restrict__ ctl) {
    __shared__ int lh[5];
    const int tid = threadIdx.x;
    const int t = blockIdx.x * 256 + tid;
    if (tid < 5) lh[tid] = 0;
    __syncthreads();
    if (t < T_REAL) atomicAdd(&lh[targets[t]], 1);
    __syncthreads();
    if (tid < 5) atomicAdd(&ctl[tid], lh[tid]);
}

// ---------------- k_scan: offsets, scatter cursors, tile classes, pad labels --
__global__ void k_scan(int* __restrict__ ctl, int* __restrict__ tcl,
                       int* __restrict__ labels) {
    __shared__ int soffs[6];
    const int tid = threadIdx.x;
    if (tid == 0) {
        int o = 0;
        for (int c = 0; c < 5; ++c) {
            soffs[c] = o; ctl[16 + c] = o; ctl[8 + c] = o;
            o += ctl[c];
        }
        soffs[5] = o; ctl[21] = o;            // == T_REAL
    }
    __syncthreads();
    for (int t = tid; t < NT; t += 256) {
        const int lo = t * 64, hi = lo + 64;
        int tc = -2;                           // mixed
        if (lo >= T_REAL) tc = -1;             // pure pad
        else {
#pragma unroll
            for (int c = 0; c < 5; ++c)
                if (lo >= soffs[c] && hi <= soffs[c + 1]) tc = c;
        }
        tcl[t] = tc;
    }
    for (int t = T_REAL + tid; t < TPAD; t += 256) labels[t] = -1;
}

// ---------------- k_rank: sorted position per pixel (wave-aggregated) --------
__global__ void k_rank(const int* __restrict__ targets, int* __restrict__ ctl,
                       int* __restrict__ rank, int* __restrict__ labels) {
    const int tid = threadIdx.x;
    const int t = blockIdx.x * 256 + tid;
    const int lane = tid & 63;
    const int c = (t < T_REAL) ? targets[t] : -1;
#pragma unroll
    for (int cl = 0; cl < 5; ++cl) {
        unsigned long long m = __ballot(c == cl);
        if (c == cl) {
            const int leader = __ffsll((unsigned long long)m) - 1;
            int base = 0;
            if (lane == leader) base = atomicAdd(&ctl[8 + cl], (int)__popcll(m));
            base = __shfl(base, leader);
            const unsigned long long below = m & ((1ull << lane) - 1ull);
            const int r = base + (int)__popcll(below);
            rank[t] = r;
            labels[r] = c;
        }
    }
}

// ---------------- k_prep: norm+transpose+scale+cast, scattered to sorted rows
__global__ void k_prep(const float* __restrict__ emb, const int* __restrict__ rank,
                       _Float16* __restrict__ feats) {
    const int tid = threadIdx.x;
    const int bx = blockIdx.x, n = blockIdx.y;

    if (bx == 59) {            // tail block: zero this n's share of pad rows
        const int r0 = T_REAL + n * 119;
        f16x8 z = {0, 0, 0, 0, 0, 0, 0, 0};
        for (int c = tid; c < 119 * 32; c += 256) {
            int rr = r0 + (c >> 5), cc = c & 31;
            *reinterpret_cast<f16x8*>(feats + (size_t)rr * CDIM + cc * 8) = z;
        }
        return;
    }

    __shared__ float tile[64][257];
    __shared__ float sspart[4][64];
    const int lane = tid & 63, w = tid >> 6;
    const int px0 = bx * 64;
    const int hw = px0 + lane;

    float ssq = 0.f;
    for (int ci = w; ci < CDIM; ci += 4) {
        float v = (hw < HW) ? emb[((size_t)(n * CDIM + ci)) * HW + hw] : 0.f;
        tile[lane][ci] = v;
        ssq += v * v;
    }
    sspart[w][lane] = ssq;
    __syncthreads();

    const int pp = tid >> 2, q = tid & 3;     // pixel-in-tile, channel quarter
    float s2 = sspart[q][pp];
    s2 += __shfl_xor(s2, 1);
    s2 += __shfl_xor(s2, 2);
    const float inv = SQRT_SCALE / fmaxf(sqrtf(s2), 1e-12f);

    const int hwp = px0 + pp;
    if (hwp < HW) {
        const int row = rank[n * HW + hwp];
        _Float16* dst = feats + (size_t)row * CDIM + q * 64;
#pragma unroll
        for (int g = 0; g < 8; ++g) {
            const int gg = g ^ q;             // spread LDS banks across q
            f16x8 o;
#pragma unroll
            for (int e = 0; e < 8; ++e) o[e] = (_Float16)(tile[pp][q * 64 + gg * 8 + e] * inv);
            *reinterpret_cast<f16x8*>(dst + gg * 8) = o;
        }
    }
}

// ---------------- k_main staging ----------------
// LDS tile: 64 j-rows x 512B (32 chunks of 16B). Slot chunk c of row j holds
// global chunk c ^ swz(j), swz(j) = (j&7) ^ (((j>>3)&3)<<1). Linear LDS dest +
// pre-swizzled global source (rule #21). 8 loads/thread at 256 threads.
__device__ __forceinline__ void stage_tile(const _Float16* __restrict__ feats, int jbase,
                                           _Float16* bufp, int tid) {
#pragma unroll
    for (int sweep = 0; sweep < 8; ++sweep) {
        int ch = sweep * 256 + tid;          // 0..2047 = 64 rows * 32 chunks
        int j  = ch >> 5;
        int c  = ch & 31;
        int swz = (j & 7) ^ (((j >> 3) & 3) << 1);
        int csrc = c ^ swz;
        const _Float16* src = feats + ((size_t)(jbase + j)) * CDIM + csrc * 8;
        __builtin_amdgcn_global_load_lds(
            (const __attribute__((address_space(1))) void*)src,
            (__attribute__((address_space(3))) void*)(bufp + (size_t)ch * 8),
            16, 0, 0);
    }
}

// ---------------- k_main: fused sim/exp/masked-rowsum (fp16, sorted labels) --
// 4 waves x 64 i-rows = 256 rows/block, 2 independent blocks/CU. B-frags in
// registers (128 VGPR), acc reused across the two j-groups. Pure-class tiles
// (234/240 after sorting) use the cheap exp2+add epilogue with one per-tile
// label compare; mixed tiles fall back to per-element label compare.
__global__ __launch_bounds__(256, 2) void k_main(const _Float16* __restrict__ feats,
                                                 const int* __restrict__ labels,
                                                 const int* __restrict__ tcl,
                                                 float2* __restrict__ partials) {
    __shared__ __align__(16) _Float16 buf[2][64 * 256];   // 2 x 32KB
    const int tid  = threadIdx.x;
    const int w    = tid >> 6, lane = tid & 63;
    const int lo   = lane & 31, hi = lane >> 5;
    const int rb = blockIdx.x, slice = blockIdx.y;
    const int ibase = rb * 256 + w * 64;

    const int labi0 = labels[ibase + lo];
    const int labi1 = labels[ibase + 32 + lo];

    // B fragments (i-side), resident all kernel.
    // 32x32x16 B layout: lane holds col = lane&31, k = (lane>>5)*8 + e.
    f16x8 b0[16], b1[16];
    {
        const f16x8* r0 = (const f16x8*)(feats + (size_t)(ibase + lo) * CDIM + hi * 8);
        const f16x8* r1 = (const f16x8*)(feats + (size_t)(ibase + 32 + lo) * CDIM + hi * 8);
#pragma unroll
        for (int ks = 0; ks < 16; ++ks) { b0[ks] = r0[ks * 2]; b1[ks] = r1[ks * 2]; }
    }

    // swizzled read addressing: chunk (2ks+hi)^swz(lo); halves offset =
    // lo*256 + ((hi^s0)<<3) + ((ks&3)^sp)<<4 + (ks&12)<<4   [+8192 for jg1]
    const int s  = (lo & 7) ^ (((lo >> 3) & 3) << 1);
    const int sp = s >> 1;
    const int x0h = (s & 1) << 3;
    int idx4[4];
#pragma unroll
    for (int m = 0; m < 4; ++m)
        idx4[m] = lo * 256 + ((hi << 3) ^ x0h) + (((m ^ sp)) << 4);

    float accA0 = 0.f, accP0 = 0.f, accA1 = 0.f, accP1 = 0.f;

    stage_tile(feats, slice * 64, &buf[0][0], tid);

#pragma unroll 1
    for (int ti = 0; ti < TPS; ++ti) {
        const int jt = slice + ti * NSL;

        __builtin_amdgcn_s_barrier();              // prev compute done everywhere
        __builtin_amdgcn_sched_barrier(0);
        if (ti + 1 < TPS) {
            stage_tile(feats, (jt + NSL) * 64, &buf[(ti + 1) & 1][0], tid);
            asm volatile("s_waitcnt vmcnt(8)" ::: "memory");  // tile ti done; ti+1 in flight
        } else {
            asm volatile("s_waitcnt vmcnt(0)" ::: "memory");
        }
        __builtin_amdgcn_s_barrier();              // tile ti visible to all waves
        __builtin_amdgcn_sched_barrier(0);

        const _Float16* bc = &buf[ti & 1][0];
        const int tc = tcl[jt];                    // block-uniform tile class
        float tT0 = 0.f, tT1 = 0.f;

#pragma unroll
        for (int jg = 0; jg < 2; ++jg) {
            const _Float16* bjg = bc + jg * 8192;
            f32x16 cA = {0,0,0,0,0,0,0,0,0,0,0,0,0,0,0,0};
            f32x16 cB = cA;
#pragma unroll
            for (int ks = 0; ks < 16; ++ks) {
                const f16x8 a = *reinterpret_cast<const f16x8*>(
                    bjg + idx4[ks & 3] + ((ks & 12) << 4));
                cA = __builtin_amdgcn_mfma_f32_32x32x16_f16(a, b0[ks], cA, 0, 0, 0);
                cB = __builtin_amdgcn_mfma_f32_32x32x16_f16(a, b1[ks], cB, 0, 0, 0);
            }
            if (tc != -2) {
                // pure-class tile: subtotal only, label test ONCE per tile
#pragma unroll
                for (int v = 0; v < 16; ++v) {
                    tT0 += exp2_fast(cA[v]);
                    tT1 += exp2_fast(cB[v]);
                }
            } else {
                // mixed tile: per-element label compare
                const int jb2 = jt * 64 + jg * 32;
#pragma unroll
                for (int q = 0; q < 4; ++q) {
                    const int4 lj = *reinterpret_cast<const int4*>(labels + jb2 + q * 8 + hi * 4);
#pragma unroll
                    for (int r = 0; r < 4; ++r) {
                        const int ljr = (r == 0) ? lj.x : (r == 1) ? lj.y : (r == 2) ? lj.z : lj.w;
                        float e0 = exp2_fast(cA[q * 4 + r]);
                        accA0 += e0;
                        accP0 += (ljr == labi0) ? e0 : 0.f;
                        float e1 = exp2_fast(cB[q * 4 + r]);
                        accA1 += e1;
                        accP1 += (ljr == labi1) ? e1 : 0.f;
                    }
                }
            }
        }
        if (tc != -2) {
            accA0 += tT0; accA1 += tT1;
            accP0 += (tc == labi0) ? tT0 : 0.f;
            accP1 += (tc == labi1) ? tT1 : 0.f;
        }
    }

    // diagonal term: ||b_i||^2 (feats pre-scaled, so this IS sim_ii*SCALE)
    float n0 = 0.f, n1 = 0.f;
#pragma unroll
    for (int ks = 0; ks < 16; ++ks)
#pragma unroll
        for (int e = 0; e < 8; ++e) {
            float v0 = (float)b0[ks][e]; n0 += v0 * v0;
            float v1 = (float)b1[ks][e]; n1 += v1 * v1;
        }
    n0 += __shfl_xor(n0, 32); n1 += __shfl_xor(n1, 32);

    // merge the two k-halves (lanes l and l^32 hold the same i)
    accA0 += __shfl_xor(accA0, 32); accP0 += __shfl_xor(accP0, 32);
    accA1 += __shfl_xor(accA1, 32); accP1 += __shfl_xor(accP1, 32);

    // subtract diagonal exactly once (owner slice of the tile containing j==i)
    if (((rb * 4 + w) & (NSL - 1)) == slice) {
        float e0 = exp2_fast(n0), e1 = exp2_fast(n1);
        accA0 -= e0; accP0 -= e0;
        accA1 -= e1; accP1 -= e1;
    }

    if (hi == 0) {
        size_t base = ((size_t)(rb * NSL + slice)) * 256 + w * 64;
        partials[base + lo]      = make_float2(accA0, accP0);
        partials[base + 32 + lo] = make_float2(accA1, accP1);
    }
}

// ---------------- k_reduce: per-row loss + global accumulate ----------------
__global__ void k_reduce(const float2* __restrict__ partials, float* __restrict__ accum) {
    const int rb = blockIdx.x;          // 60
    const int rl = threadIdx.x;         // 256
    const int t  = rb * 256 + rl;
    float sA = -NPADJ, sP = 0.f;        // pad columns contribute exp2(0)=1 each
#pragma unroll
    for (int s = 0; s < NSL; ++s) {
        float2 v = partials[((size_t)(rb * NSL + s)) * 256 + rl];
        sA += v.x; sP += v.y;
    }
    float per = 0.f, cnt = 0.f;
    if (t < T_REAL && sP > 0.f) {
        per = logf(sA) - logf(sP);      // = -(log(pos) - log(all))
        cnt = 1.f;
    }
#pragma unroll
    for (int off = 32; off >= 1; off >>= 1) {
        per += __shfl_xor(per, off);
        cnt += __shfl_xor(cnt, off);
    }
    if ((threadIdx.x & 63) == 0) { atomicAdd(&accum[0], per); atomicAdd(&accum[1], cnt); }
}

__global__ void k_final(const float* __restrict__ accum, float* __restrict__ out) {
    out[0] = accum[0] / fmaxf(accum[1], 1.0f);
}

// ---------------- launch ----------------
extern "C" void kernel_launch(void* const* d_in, const int* in_sizes, int n_in,
                              void* d_out, int out_size, void* d_ws, size_t ws_size,
                              hipStream_t stream) {
    const float* emb     = (const float*)d_in[0];
    const int*   targets = (const int*)d_in[1];
    float*       out     = (float*)d_out;
    char*        ws      = (char*)d_ws;

    _Float16* feats    = (_Float16*)(ws + OFF_FEATS);
    int*      labels   = (int*)(ws + OFF_LAB);
    int*      rank     = (int*)(ws + OFF_RANK);
    int*      ctl      = (int*)(ws + OFF_CTL);
    int*      tcl      = (int*)(ws + OFF_TCL);
    float2*   partials = (float2*)(ws + OFF_PART);
    float*    accum    = (float*)(ws + OFF_ACC);

    k_zero  <<<dim3(1),        dim3(64),  0, stream>>>(ctl, accum);
    k_hist  <<<dim3(59),       dim3(256), 0, stream>>>(targets, ctl);
    k_scan  <<<dim3(1),        dim3(256), 0, stream>>>(ctl, tcl, labels);
    k_rank  <<<dim3(59),       dim3(256), 0, stream>>>(targets, ctl, rank, labels);
    k_prep  <<<dim3(60, 4),    dim3(256), 0, stream>>>(emb, rank, feats);
    k_main  <<<dim3(NRB, NSL), dim3(256), 0, stream>>>(feats, labels, tcl, partials);
    k_reduce<<<dim3(NRB),      dim3(256), 0, stream>>>(partials, accum);
    k_final <<<dim3(1),        dim3(1),   0, stream>>>(accum, out);
}